// Round 1
// 178.118 us; speedup vs baseline: 1.1053x; 1.1053x over previous
//
#include <hip/hip_runtime.h>

namespace {

typedef _Float16 f16;
typedef __attribute__((ext_vector_type(2))) _Float16 f16x2;
typedef __attribute__((ext_vector_type(4))) _Float16 f16x4;
typedef __attribute__((ext_vector_type(8))) _Float16 f16x8;
typedef __attribute__((ext_vector_type(4))) float f32x4;
typedef __attribute__((ext_vector_type(16))) float f32x16;

constexpr int kDim   = 1024;
constexpr int kHeads = 16;
constexpr int kHd    = 64;
constexpr int kB     = 2;
constexpr int kL     = 1024;
constexpr int kS     = 2048;

// ---------------- prep: casts (y<3) + weight transposes (y>=3) ------------
struct PrepArgs {
  const float* csrc[3];
  f16* cdst[3];
  int cn[3];
  const float* w[4];
  f16* wt[4];
};

__global__ __launch_bounds__(256) void prep(PrepArgs a) {
  __shared__ float T[32][33];
  const int y = blockIdx.y;
  if (y < 3) {
    const int i = (blockIdx.x * 256 + threadIdx.x) * 8;
    if (i >= a.cn[y]) return;
    const float* __restrict__ src = a.csrc[y];
    float4 v0 = *(const float4*)(src + i);
    float4 v1 = *(const float4*)(src + i + 4);
    f16x8 h = {(f16)v0.x, (f16)v0.y, (f16)v0.z, (f16)v0.w,
               (f16)v1.x, (f16)v1.y, (f16)v1.z, (f16)v1.w};
    *(f16x8*)(a.cdst[y] + i) = h;
  } else {
    if (blockIdx.x >= 1024) return;
    const int z = y - 3;
    const float* __restrict__ W = a.w[z];
    f16* __restrict__ Wt = a.wt[z];
    const int n0 = (blockIdx.x & 31) * 32;
    const int k0 = (blockIdx.x >> 5) * 32;
    const int r = threadIdx.x >> 3;
    const int c = (threadIdx.x & 7) * 4;
    float4 v = *(const float4*)(W + (size_t)(k0 + r) * kDim + n0 + c);
    T[c + 0][r] = v.x; T[c + 1][r] = v.y; T[c + 2][r] = v.z; T[c + 3][r] = v.w;
    __syncthreads();
    f16x4 h = {(f16)T[r][c], (f16)T[r][c + 1], (f16)T[r][c + 2], (f16)T[r][c + 3]};
    *(f16x4*)(Wt + (size_t)(n0 + r) * kDim + k0 + c) = h;
  }
}

// ------------- fused projection GEMMs, f16 operands, reg-prefetch ---------
// Flat 640-block grid: [0,128) Q, [128,384) K, [384,640) V^T.
struct ProjArgs {
  const f16* A[3];
  const f16* Bt[3];
  f16* C[3];
};

__global__ __launch_bounds__(256) void gemm_proj(ProjArgs p) {
  constexpr int K = kDim;
  constexpr int NI = K / 32;
  int bx = blockIdx.x;
  int z, m0, n0, Nz;
  if (bx < 128)      { z = 0; m0 = (bx >> 3) * 128; n0 = (bx & 7) * 128; Nz = kDim; }
  else if (bx < 384) { bx -= 128; z = 1; m0 = (bx >> 3) * 128; n0 = (bx & 7) * 128; Nz = kDim; }
  else               { bx -= 384; z = 2; m0 = (bx >> 5) * 128; n0 = (bx & 31) * 128; Nz = kB * kS; }
  const f16* __restrict__ A  = p.A[z];
  const f16* __restrict__ Bt = p.Bt[z];
  f16* __restrict__ C = p.C[z];

  __shared__ __align__(16) f16 As[2][128 * 32];
  __shared__ __align__(16) f16 Bs[2][128 * 32];
  const int t = threadIdx.x;
  const int lane = t & 63;
  const int wave = t >> 6;
  const int wm = (wave >> 1) * 64;
  const int wn = (wave & 1) * 64;
  const int col = lane & 15;
  const int quad = lane >> 4;

  f32x4 acc[4][4];
#pragma unroll
  for (int i = 0; i < 4; ++i)
#pragma unroll
    for (int j = 0; j < 4; ++j) acc[i][j] = (f32x4){0.f, 0.f, 0.f, 0.f};

  const int c0 = t, c1 = t + 256;
  const f16* a0 = A + (size_t)(m0 + (c0 >> 2)) * K + (c0 & 3) * 8;
  const f16* a1 = A + (size_t)(m0 + (c1 >> 2)) * K + (c1 & 3) * 8;
  const f16* b0 = Bt + (size_t)(n0 + (c0 >> 2)) * K + (c0 & 3) * 8;
  const f16* b1 = Bt + (size_t)(n0 + (c1 >> 2)) * K + (c1 & 3) * 8;

  {
    f16x8 ra0 = *(const f16x8*)(a0);
    f16x8 ra1 = *(const f16x8*)(a1);
    f16x8 rb0 = *(const f16x8*)(b0);
    f16x8 rb1 = *(const f16x8*)(b1);
    *(f16x8*)(As[0] + c0 * 8) = ra0;
    *(f16x8*)(As[0] + c1 * 8) = ra1;
    *(f16x8*)(Bs[0] + c0 * 8) = rb0;
    *(f16x8*)(Bs[0] + c1 * 8) = rb1;
  }

  for (int i = 0; i < NI; ++i) {
    const int cur = i & 1;
    f16x8 na0, na1, nb0, nb1;
    if (i + 1 < NI) {
      const int ko = (i + 1) * 32;
      na0 = *(const f16x8*)(a0 + ko);
      na1 = *(const f16x8*)(a1 + ko);
      nb0 = *(const f16x8*)(b0 + ko);
      nb1 = *(const f16x8*)(b1 + ko);
    }
    __syncthreads();

    f16x8 af[4], bf[4];
#pragma unroll
    for (int mt = 0; mt < 4; ++mt)
      af[mt] = *(const f16x8*)(As[cur] + (wm + mt * 16 + col) * 32 + quad * 8);
#pragma unroll
    for (int nt = 0; nt < 4; ++nt)
      bf[nt] = *(const f16x8*)(Bs[cur] + (wn + nt * 16 + col) * 32 + quad * 8);
#pragma unroll
    for (int mt = 0; mt < 4; ++mt)
#pragma unroll
      for (int nt = 0; nt < 4; ++nt)
        acc[mt][nt] = __builtin_amdgcn_mfma_f32_16x16x32_f16(
            af[mt], bf[nt], acc[mt][nt], 0, 0, 0);

    if (i + 1 < NI) {
      const int nxt = 1 - cur;
      *(f16x8*)(As[nxt] + c0 * 8) = na0;
      *(f16x8*)(As[nxt] + c1 * 8) = na1;
      *(f16x8*)(Bs[nxt] + c0 * 8) = nb0;
      *(f16x8*)(Bs[nxt] + c1 * 8) = nb1;
    }
  }

  const int crow = m0 + wm + quad * 4;
  const int ccol = n0 + wn + col;
#pragma unroll
  for (int mt = 0; mt < 4; ++mt)
#pragma unroll
    for (int nt = 0; nt < 4; ++nt)
#pragma unroll
      for (int r = 0; r < 4; ++r)
        C[(size_t)(crow + mt * 16 + r) * Nz + ccol + nt * 16] =
            (f16)acc[mt][nt][r];
}

// --------- output projection: 64x64 tiles, grid 512 = 2 blocks/CU ---------
__global__ __launch_bounds__(256) void gemm_out(
    const f16* __restrict__ A, const f16* __restrict__ Bt,
    const float* __restrict__ bias, float* __restrict__ C, int M, int N, int K)
{
  __shared__ __align__(16) f16 As[2][64 * 32];
  __shared__ __align__(16) f16 Bs[2][64 * 32];
  const int t = threadIdx.x;
  const int lane = t & 63;
  const int wave = t >> 6;
  const int n0 = blockIdx.x * 64;
  const int m0 = blockIdx.y * 64;
  const int wm = (wave >> 1) * 32;
  const int wn = (wave & 1) * 32;
  const int col = lane & 15;
  const int quad = lane >> 4;
  const int NI = K / 32;

  f32x4 acc[2][2];
#pragma unroll
  for (int i = 0; i < 2; ++i)
#pragma unroll
    for (int j = 0; j < 2; ++j) acc[i][j] = (f32x4){0.f, 0.f, 0.f, 0.f};

  const f16* a0 = A + (size_t)(m0 + (t >> 2)) * K + (t & 3) * 8;
  const f16* b0 = Bt + (size_t)(n0 + (t >> 2)) * K + (t & 3) * 8;

  {
    f16x8 ra0 = *(const f16x8*)(a0);
    f16x8 rb0 = *(const f16x8*)(b0);
    *(f16x8*)(As[0] + t * 8) = ra0;
    *(f16x8*)(Bs[0] + t * 8) = rb0;
  }

  for (int i = 0; i < NI; ++i) {
    const int cur = i & 1;
    f16x8 na0, nb0;
    if (i + 1 < NI) {
      const int ko = (i + 1) * 32;
      na0 = *(const f16x8*)(a0 + ko);
      nb0 = *(const f16x8*)(b0 + ko);
    }
    __syncthreads();

    f16x8 af[2], bf[2];
#pragma unroll
    for (int mt = 0; mt < 2; ++mt)
      af[mt] = *(const f16x8*)(As[cur] + (wm + mt * 16 + col) * 32 + quad * 8);
#pragma unroll
    for (int nt = 0; nt < 2; ++nt)
      bf[nt] = *(const f16x8*)(Bs[cur] + (wn + nt * 16 + col) * 32 + quad * 8);
#pragma unroll
    for (int mt = 0; mt < 2; ++mt)
#pragma unroll
      for (int nt = 0; nt < 2; ++nt)
        acc[mt][nt] = __builtin_amdgcn_mfma_f32_16x16x32_f16(
            af[mt], bf[nt], acc[mt][nt], 0, 0, 0);

    if (i + 1 < NI) {
      const int nxt = 1 - cur;
      *(f16x8*)(As[nxt] + t * 8) = na0;
      *(f16x8*)(Bs[nxt] + t * 8) = nb0;
    }
  }

  const int crow = m0 + wm + quad * 4;
  const int ccol = n0 + wn + col;
#pragma unroll
  for (int mt = 0; mt < 2; ++mt)
#pragma unroll
    for (int nt = 0; nt < 2; ++nt) {
      const float bv = bias[ccol + nt * 16];
#pragma unroll
      for (int r = 0; r < 4; ++r)
        C[(size_t)(crow + mt * 16 + r) * N + ccol + nt * 16] =
            acc[mt][nt][r] + bv;
    }
}

// ---------------- MFMA flash attention v4 ---------------------------------
// 32x32x16 MFMAs, swapped QK^T (S^T), in-register softmax (no P LDS trip),
// split-S across wave pairs: waves {0,1} s in [0,1024), waves {2,3} [1024,2048).
// Linear merge (exp without running max) through a one-time LDS scratch.
// Grid (32 bh, 16 qtile) = 512 blocks = 2/CU; LDS 73.7 KB -> 2 blocks/CU.

__device__ inline unsigned pk2f(float a, float b) {
  union { f16x2 h; unsigned u; } c;
  c.h = f16x2{(f16)a, (f16)b};
  return c.u;
}

__device__ inline void swap32(unsigned& x, unsigned& y) {
  // lanes 0-31 of y exchange with lanes 32-63 of x.
  asm("v_permlane32_swap_b32 %0, %1" : "+v"(x), "+v"(y));
}

__global__ __launch_bounds__(256, 2) void flash_attn_mfma4(
    const f16* __restrict__ q, const f16* __restrict__ k,
    const f16* __restrict__ vT, f16* __restrict__ x)
{
  constexpr int LP  = 72;              // 64 data + 8 pad f16 per row
  constexpr int NT2 = (kS / 2) / 64;   // 16 iterations over this wave's S-half
  __shared__ __align__(16) f16 Kt[2][2][64 * LP];  // [dbuf][s-half][row*LP]
  __shared__ __align__(16) f16 Vt[2][2][64 * LP];

  const int t    = threadIdx.x;
  const int lane = t & 63;
  const int wave = t >> 6;
  const int wq   = wave & 1;    // q sub-tile (rows wq*32 .. +31)
  const int wh   = wave >> 1;   // s half
  const int ln   = lane & 31;
  const int hi   = lane >> 5;
  const int bh   = blockIdx.x;
  const int l0   = blockIdx.y * 64;
  const int h    = bh & (kHeads - 1);
  const int b    = bh >> 4;

  // Q fragment (B-operand of swapped QK^T): lane holds Q[q=ln][d=ks*16+hi*8+u]
  f16x8 qf[4];
  {
    const f16* src = q + ((size_t)b * kL + l0 + wq * 32 + ln) * kDim + h * kHd + hi * 8;
#pragma unroll
    for (int ks = 0; ks < 4; ++ks) {
      qf[ks] = *(const f16x8*)(src + ks * 16);
#pragma unroll
      for (int u = 0; u < 8; ++u) qf[ks][u] *= (f16)0.125f;
    }
  }

  // Cooperative staging: all 256 threads stage K/V tiles of BOTH halves.
  const int srow = t >> 2;
  const int scol = (t & 3) * 16;
  const f16* kb = k + ((size_t)b * kS + srow) * kDim + h * kHd + scol;
  const f16* vb = vT + ((size_t)(h * kHd + srow)) * (kB * kS) + b * kS + scol;
  const size_t kHalf = (size_t)1024 * kDim;

  f32x16 accO[2];
#pragma unroll
  for (int dt = 0; dt < 2; ++dt)
#pragma unroll
    for (int r = 0; r < 16; ++r) accO[dt][r] = 0.f;
  float lsum = 0.f;

  f16x8 kh0a, kh0b, kh1a, kh1b, vh0a, vh0b, vh1a, vh1b;

#define STAGE_LOAD(i)                                                   \
  { const f16* kp0 = kb + (size_t)(i) * 64 * kDim;                      \
    const f16* kp1 = kp0 + kHalf;                                       \
    const f16* vp0 = vb + (i) * 64;                                     \
    const f16* vp1 = vp0 + 1024;                                        \
    kh0a = *(const f16x8*)(kp0); kh0b = *(const f16x8*)(kp0 + 8);       \
    kh1a = *(const f16x8*)(kp1); kh1b = *(const f16x8*)(kp1 + 8);       \
    vh0a = *(const f16x8*)(vp0); vh0b = *(const f16x8*)(vp0 + 8);       \
    vh1a = *(const f16x8*)(vp1); vh1b = *(const f16x8*)(vp1 + 8); }

#define STAGE_WRITE(bf)                                                 \
  { f16* kd0 = &Kt[bf][0][srow * LP + scol];                            \
    f16* kd1 = &Kt[bf][1][srow * LP + scol];                            \
    f16* vd0 = &Vt[bf][0][srow * LP + scol];                            \
    f16* vd1 = &Vt[bf][1][srow * LP + scol];                            \
    *(f16x8*)(kd0) = kh0a; *(f16x8*)(kd0 + 8) = kh0b;                   \
    *(f16x8*)(kd1) = kh1a; *(f16x8*)(kd1 + 8) = kh1b;                   \
    *(f16x8*)(vd0) = vh0a; *(f16x8*)(vd0 + 8) = vh0b;                   \
    *(f16x8*)(vd1) = vh1a; *(f16x8*)(vd1 + 8) = vh1b; }

  STAGE_LOAD(0);
  STAGE_WRITE(0);

  for (int i = 0; i < NT2; ++i) {
    const int cur = i & 1;
    if (i + 1 < NT2) STAGE_LOAD(i + 1);
    __syncthreads();

    const f16* Kc = &Kt[cur][wh][0];
    const f16* Vc = &Vt[cur][wh][0];

    f16x8 pf[4];
#pragma unroll
    for (int sub = 0; sub < 2; ++sub) {
      // swapped QK^T: C[s][q], q = ln, s = sub*32 + (r&3) + 8*(r>>2) + 4*hi
      f32x16 s;
#pragma unroll
      for (int r = 0; r < 16; ++r) s[r] = 0.f;
      __builtin_amdgcn_s_setprio(1);
#pragma unroll
      for (int ks = 0; ks < 4; ++ks) {
        f16x8 kf = *(const f16x8*)(Kc + (sub * 32 + ln) * LP + ks * 16 + hi * 8);
        s = __builtin_amdgcn_mfma_f32_32x32x16_f16(kf, qf[ks], s, 0, 0, 0);
      }
      __builtin_amdgcn_s_setprio(0);

      float pp[16];
#pragma unroll
      for (int r = 0; r < 16; ++r) { pp[r] = __expf(s[r]); lsum += pp[r]; }

      // Rebuild PV A-fragment in registers: per k-step ks=sub*2+kk the lane
      // needs s = 16*ks + 8*hi + u; it owns half, lane^32 owns the other.
#pragma unroll
      for (int kk = 0; kk < 2; ++kk) {
        unsigned a0 = pk2f(pp[8 * kk + 0], pp[8 * kk + 1]);
        unsigned a1 = pk2f(pp[8 * kk + 2], pp[8 * kk + 3]);
        unsigned b0 = pk2f(pp[8 * kk + 4], pp[8 * kk + 5]);
        unsigned b1 = pk2f(pp[8 * kk + 6], pp[8 * kk + 7]);
        swap32(a0, b0);
        swap32(a1, b1);
        union { unsigned u[4]; f16x8 v; } w;
        w.u[0] = a0; w.u[1] = a1; w.u[2] = b0; w.u[3] = b1;
        pf[sub * 2 + kk] = w.v;
      }
    }

    __builtin_amdgcn_s_setprio(1);
#pragma unroll
    for (int dt = 0; dt < 2; ++dt)
#pragma unroll
      for (int ks = 0; ks < 4; ++ks) {
        f16x8 vf = *(const f16x8*)(Vc + (dt * 32 + ln) * LP + ks * 16 + hi * 8);
        accO[dt] = __builtin_amdgcn_mfma_f32_32x32x16_f16(pf[ks], vf, accO[dt], 0, 0, 0);
      }
    __builtin_amdgcn_s_setprio(0);

    if (i + 1 < NT2) STAGE_WRITE(1 - cur);
  }
#undef STAGE_LOAD
#undef STAGE_WRITE

  // ---- merge the two S-halves (linear: plain add of accO and l) ----
  lsum += __shfl_xor(lsum, 32);          // merge hi-half partial row sums
  __syncthreads();                       // done reading Kt -> reuse as scratch
  float* sc = (float*)&Kt[0][0][0];      // 128 lanes * 33 floats (pad) = 16.9KB
  float* sl = sc + 128 * 33;
  if (wh == 1) {
    float* dst = sc + (wq * 64 + lane) * 33;
#pragma unroll
    for (int dt = 0; dt < 2; ++dt)
#pragma unroll
      for (int r = 0; r < 16; ++r) dst[dt * 16 + r] = accO[dt][r];
    sl[wq * 64 + lane] = lsum;
  }
  __syncthreads();
  if (wh == 0) {
    const float* src = sc + (wq * 64 + lane) * 33;
#pragma unroll
    for (int dt = 0; dt < 2; ++dt)
#pragma unroll
      for (int r = 0; r < 16; ++r) accO[dt][r] += src[dt * 16 + r];
    const float inv = 1.f / (lsum + sl[wq * 64 + lane]);  // valid for row ln
    const size_t row0 = (size_t)b * kL + l0 + wq * 32;
    f16* xb = x + row0 * kDim + h * kHd + ln;
#pragma unroll
    for (int r = 0; r < 16; ++r) {
      const int qr = (r & 3) + 8 * (r >> 2) + 4 * hi;   // C row of 32x32 mfma
      const float invr = __shfl(inv, qr);
      xb[(size_t)qr * kDim]      = (f16)(accO[0][r] * invr);
      xb[(size_t)qr * kDim + 32] = (f16)(accO[1][r] * invr);
    }
  }
}

}  // namespace

extern "C" void kernel_launch(void* const* d_in, const int* in_sizes, int n_in,
                              void* d_out, int out_size, void* d_ws, size_t ws_size,
                              hipStream_t stream) {
  const float* query = (const float*)d_in[0];
  const float* key   = (const float*)d_in[1];
  const float* value = (const float*)d_in[2];
  const float* Wq    = (const float*)d_in[3];
  const float* Wk    = (const float*)d_in[4];
  const float* Wv    = (const float*)d_in[5];
  const float* Wo    = (const float*)d_in[6];
  const float* bo    = (const float*)d_in[7];
  float* out = (float*)d_out;

  f16* ws = (f16*)d_ws;
  f16* qh  = ws;
  f16* kh  = qh + (size_t)kB * kL * kDim;
  f16* vh  = kh + (size_t)kB * kS * kDim;
  f16* wqt = vh + (size_t)kB * kS * kDim;
  f16* wkt = wqt + (size_t)kDim * kDim;
  f16* wvt = wkt + (size_t)kDim * kDim;
  f16* wot = wvt + (size_t)kDim * kDim;
  f16* qp  = wot + (size_t)kDim * kDim;
  f16* kp  = qp + (size_t)kB * kL * kDim;
  f16* vpT = kp + (size_t)kB * kS * kDim;   // [kDim][kB*kS] = V^T
  f16* xh  = vpT + (size_t)kB * kS * kDim;

  PrepArgs pr;
  pr.csrc[0] = query; pr.cdst[0] = qh; pr.cn[0] = kB * kL * kDim;
  pr.csrc[1] = key;   pr.cdst[1] = kh; pr.cn[1] = kB * kS * kDim;
  pr.csrc[2] = value; pr.cdst[2] = vh; pr.cn[2] = kB * kS * kDim;
  pr.w[0] = Wq; pr.wt[0] = wqt;
  pr.w[1] = Wk; pr.wt[1] = wkt;
  pr.w[2] = Wv; pr.wt[2] = wvt;
  pr.w[3] = Wo; pr.wt[3] = wot;
  prep<<<dim3(2048, 7), 256, 0, stream>>>(pr);

  ProjArgs pa;
  pa.A[0] = qh;  pa.Bt[0] = wqt; pa.C[0] = qp;
  pa.A[1] = kh;  pa.Bt[1] = wkt; pa.C[1] = kp;
  pa.A[2] = wvt; pa.Bt[2] = vh;  pa.C[2] = vpT;
  gemm_proj<<<dim3(640), 256, 0, stream>>>(pa);

  flash_attn_mfma4<<<dim3(kB * kHeads, kL / 64), 256, 0, stream>>>(
      qp, kp, vpT, xh);

  gemm_out<<<dim3(kDim / 64, (kB * kL) / 64), 256, 0, stream>>>(
      xh, wot, bo, out, kB * kL, kDim, kDim);
}